// Round 1
// baseline (260.816 us; speedup 1.0000x reference)
//
#include <hip/hip_runtime.h>

#define NXD 128
#define NYD 128
#define SRC_XD 64
#define SRC_YD 64
#define T_STEPSD 256
#define BATCHD 8
#define N_PROBESD 4

typedef float v2f __attribute__((ext_vector_type(2)));

// DPP cross-lane single shifts across the full wave64.
// WAVE_SHR1 (0x138): lane i <- lane i-1, lane0 -> 0 (bound_ctrl)
// WAVE_SHL1 (0x130): lane i <- lane i+1, lane63 -> 0
// Zero-fill matches the conv 'SAME' zero padding at col -1 / col 128.
__device__ __forceinline__ float dpp_from_lower(float v) {
    return __int_as_float(__builtin_amdgcn_update_dpp(0, __float_as_int(v), 0x138, 0xF, 0xF, true));
}
__device__ __forceinline__ float dpp_from_upper(float v) {
    return __int_as_float(__builtin_amdgcn_update_dpp(0, __float_as_int(v), 0x130, 0xF, 0xF, true));
}

// One row update (2 cells), packed-f32 friendly:
//   lap = up + dn + {lf + Y.y, Y.x + rt} - 4*Y ;  Z = K*lap + (C2 + K2*Z)
#define ROW(up, dn, Yr, Zr, Kr) { \
    const float lf = dpp_from_lower((Yr).y); \
    const float rt = dpp_from_upper((Yr).x); \
    v2f cross; cross.x = lf + (Yr).y; cross.y = (Yr).x + rt; \
    const v2f lap = (up) + (dn) + cross - 4.0f * (Yr); \
    (Zr) = (Kr) * lap + (C2v + K2v * (Zr)); \
}

// Wave-uniform 16-way register select over the OWNED rows (local i = pro+4).
#define PSEL(ro, Z, pv) switch (ro) { \
    case 0:  pv = (Z##4);  break; \
    case 1:  pv = (Z##5);  break; \
    case 2:  pv = (Z##6);  break; \
    case 3:  pv = (Z##7);  break; \
    case 4:  pv = (Z##8);  break; \
    case 5:  pv = (Z##9);  break; \
    case 6:  pv = (Z##10); break; \
    case 7:  pv = (Z##11); break; \
    case 8:  pv = (Z##12); break; \
    case 9:  pv = (Z##13); break; \
    case 10: pv = (Z##14); break; \
    case 11: pv = (Z##15); break; \
    case 12: pv = (Z##16); break; \
    case 13: pv = (Z##17); break; \
    default: pv = (Z##18); break; \
    case 15: pv = (Z##19); break; \
}

// ---- Temporal blocking (ghost-zone) scheme ----
// Local register rows i = 0..23 map to global rows 16*w + i - 4.
// Owned rows: i = 4..19. Ghost: i = 0..3 (below), 20..23 (above).
// Every step computes the FIXED range i = 1..22; staleness of the outermost
// ghost makes validity shrink inward 1 row/step:
//   after step1: valid 1..22, step2: 2..21, step3: 3..20, step4: 4..19 = owned.
// So owned rows are valid at EVERY step (probes/source read only owned rows,
// except wave 3's replicated source copy at i=20, valid through step 3 whose
// value is consumed; step-4 garbage there is overwritten at the exchange).
// One LDS exchange (+2 barriers) per 4 steps replaces 4 barrier round-trips.
//
// Boundary: wave 0 pins i=1..3 (i=0 never written, stays 0), wave 7 pins
// i=20..22 to zero each step -- this reproduces the conv 'SAME' zero padding.
// Source row 64 is local i=4 in wave 4 (owner) and ghost i=20 in wave 3;
// BOTH add x[t] so replicated values stay bit-identical to the owner's.
#define STEP(Y, Z, tt) { \
    ROW(Y##0,  Y##2,  Y##1,  Z##1,  k1) \
    ROW(Y##1,  Y##3,  Y##2,  Z##2,  k2) \
    ROW(Y##2,  Y##4,  Y##3,  Z##3,  k3) \
    ROW(Y##3,  Y##5,  Y##4,  Z##4,  k4) \
    ROW(Y##4,  Y##6,  Y##5,  Z##5,  k5) \
    ROW(Y##5,  Y##7,  Y##6,  Z##6,  k6) \
    ROW(Y##6,  Y##8,  Y##7,  Z##7,  k7) \
    ROW(Y##7,  Y##9,  Y##8,  Z##8,  k8) \
    ROW(Y##8,  Y##10, Y##9,  Z##9,  k9) \
    ROW(Y##9,  Y##11, Y##10, Z##10, k10) \
    ROW(Y##10, Y##12, Y##11, Z##11, k11) \
    ROW(Y##11, Y##13, Y##12, Z##12, k12) \
    ROW(Y##12, Y##14, Y##13, Z##13, k13) \
    ROW(Y##13, Y##15, Y##14, Z##14, k14) \
    ROW(Y##14, Y##16, Y##15, Z##15, k15) \
    ROW(Y##15, Y##17, Y##16, Z##16, k16) \
    ROW(Y##16, Y##18, Y##17, Z##17, k17) \
    ROW(Y##17, Y##19, Y##18, Z##18, k18) \
    ROW(Y##18, Y##20, Y##19, Z##19, k19) \
    ROW(Y##19, Y##21, Y##20, Z##20, k20) \
    ROW(Y##20, Y##22, Y##21, Z##21, k21) \
    ROW(Y##21, Y##23, Y##22, Z##22, k22) \
    if (w == 0) { Z##1 = zz; Z##2 = zz; Z##3 = zz; } \
    if (w == 7) { Z##20 = zz; Z##21 = zz; Z##22 = zz; } \
    if (isw4) { if (srcl) (Z##4).x  += xs[tt]; } \
    if (isw3) { if (srcl) (Z##20).x += xs[tt]; } \
    if (whas0) { v2f pv; PSEL(pro0s, Z, pv) accv0 += pv * pv; } \
    if (whas1) { v2f pv; PSEL(pro1s, Z, pv) accv1 += pv * pv; } \
    if (whas2) { v2f pv; PSEL(pro2s, Z, pv) accv2 += pv * pv; } \
    if (whas3) { v2f pv; PSEL(pro3s, Z, pv) accv3 += pv * pv; } \
}

// Exchange after each 4-step block: a = field(t+4), b = field(t+3).
// Wave w publishes: Y(a) i=4..7 -> slots 0..3, Y i=16..19 -> slots 4..7,
//                   Z(b) i=4..6 -> slots 8..10, Z i=17..19 -> slots 11..13.
// Wave w reads: upper ghost from w+1 slots {0..3, 8..10},
//               lower ghost from w-1 slots {4..7, 11..13}.
#define EXCHANGE { \
    *(v2f*)&ex[w][0][colb]  = a4;  *(v2f*)&ex[w][1][colb]  = a5; \
    *(v2f*)&ex[w][2][colb]  = a6;  *(v2f*)&ex[w][3][colb]  = a7; \
    *(v2f*)&ex[w][4][colb]  = a16; *(v2f*)&ex[w][5][colb]  = a17; \
    *(v2f*)&ex[w][6][colb]  = a18; *(v2f*)&ex[w][7][colb]  = a19; \
    *(v2f*)&ex[w][8][colb]  = b4;  *(v2f*)&ex[w][9][colb]  = b5; \
    *(v2f*)&ex[w][10][colb] = b6;  *(v2f*)&ex[w][11][colb] = b17; \
    *(v2f*)&ex[w][12][colb] = b18; *(v2f*)&ex[w][13][colb] = b19; \
    __syncthreads(); \
    if (w < 7) { \
        a20 = *(const v2f*)&ex[w + 1][0][colb];  a21 = *(const v2f*)&ex[w + 1][1][colb]; \
        a22 = *(const v2f*)&ex[w + 1][2][colb];  a23 = *(const v2f*)&ex[w + 1][3][colb]; \
        b20 = *(const v2f*)&ex[w + 1][8][colb];  b21 = *(const v2f*)&ex[w + 1][9][colb]; \
        b22 = *(const v2f*)&ex[w + 1][10][colb]; \
    } else { \
        a20 = zz; a21 = zz; a22 = zz; a23 = zz; b20 = zz; b21 = zz; b22 = zz; \
    } \
    if (w > 0) { \
        a0 = *(const v2f*)&ex[w - 1][4][colb];   a1 = *(const v2f*)&ex[w - 1][5][colb]; \
        a2 = *(const v2f*)&ex[w - 1][6][colb];   a3 = *(const v2f*)&ex[w - 1][7][colb]; \
        b1 = *(const v2f*)&ex[w - 1][11][colb];  b2 = *(const v2f*)&ex[w - 1][12][colb]; \
        b3 = *(const v2f*)&ex[w - 1][13][colb]; \
    } else { \
        a0 = zz; a1 = zz; a2 = zz; a3 = zz; b1 = zz; b2 = zz; b3 = zz; \
    } \
    __syncthreads(); \
}

// 512 threads = 8 waves = 2 waves/EU = 1 block/CU. 2 waves/EU -> 256 arch
// VGPRs/wave; state is ~170 regs (24+24 row pairs + 22 K + accs) and fits.
__global__ __launch_bounds__(512, 2) void wave_sim(
        const float* __restrict__ x,        // (T,B)
        const float* __restrict__ c,        // (NX,NY)
        const int*   __restrict__ probes,   // (4,2) int
        float* __restrict__ partial)        // (B,4)
{
    __shared__ float ex[8][14][NYD];        // 57344 B halo-exchange buffer
    __shared__ float xs[T_STEPSD];

    const int tid = threadIdx.x;
    const int w = tid >> 6;       // wave 0..7, owns global rows 16w..16w+15
    const int l = tid & 63;       // lane, owns cols 2l, 2l+1
    const int b = blockIdx.x;

    const float dt = 0.5f, bdamp = 0.005f;
    const float denom = 1.0f / (dt * dt) + 0.5f * bdamp / dt;  // 4.005
    const float inv_denom = 1.0f / denom;
    const float C2 = 2.0f * inv_denom;
    const float K2 = (-1.0f - dt * bdamp) * inv_denom;
    const float KL = dt * dt * inv_denom;
    v2f C2v; C2v.x = C2; C2v.y = C2;
    v2f K2v; K2v.x = K2; K2v.y = K2;

    if (tid < T_STEPSD) xs[tid] = x[tid * BATCHD + b];

    const int rowbase = w * 16;
    const int colb = 2 * l;
    // K for all computed rows i=1..22 (global row rowbase+i-4, edge-clamped:
    // clamped rows are only used by ghost computations whose results are
    // pinned to zero / overwritten, values irrelevant).
#define LOADK(r) \
    v2f k##r; { \
        int gr = rowbase + (r) - 4; \
        gr = gr < 0 ? 0 : (gr > NXD - 1 ? NXD - 1 : gr); \
        const v2f cc = *(const v2f*)&c[gr * NYD + colb]; \
        k##r = KL * cc * cc; \
    }
    LOADK(1) LOADK(2) LOADK(3) LOADK(4) LOADK(5) LOADK(6) LOADK(7) LOADK(8)
    LOADK(9) LOADK(10) LOADK(11) LOADK(12) LOADK(13) LOADK(14) LOADK(15)
    LOADK(16) LOADK(17) LOADK(18) LOADK(19) LOADK(20) LOADK(21) LOADK(22)
#undef LOADK

    v2f zz; zz.x = 0.0f; zz.y = 0.0f;
    v2f a0 = zz, a1 = zz, a2 = zz, a3 = zz, a4 = zz, a5 = zz, a6 = zz, a7 = zz,
        a8 = zz, a9 = zz, a10 = zz, a11 = zz, a12 = zz, a13 = zz, a14 = zz,
        a15 = zz, a16 = zz, a17 = zz, a18 = zz, a19 = zz, a20 = zz, a21 = zz,
        a22 = zz, a23 = zz;
    v2f b0 = zz, b1 = zz, b2 = zz, b3 = zz, b4 = zz, b5 = zz, b6 = zz, b7 = zz,
        b8 = zz, b9 = zz, b10 = zz, b11 = zz, b12 = zz, b13 = zz, b14 = zz,
        b15 = zz, b16 = zz, b17 = zz, b18 = zz, b19 = zz, b20 = zz, b21 = zz,
        b22 = zz, b23 = zz;

    // probes: coordinates are wave-uniform (same global load in every lane)
    const int px0 = probes[0] & 127, py0 = probes[1] & 127;
    const int px1 = probes[2] & 127, py1 = probes[3] & 127;
    const int px2 = probes[4] & 127, py2 = probes[5] & 127;
    const int px3 = probes[6] & 127, py3 = probes[7] & 127;
    const bool own0 = ((px0 >> 4) == w) && ((py0 >> 1) == l);
    const bool own1 = ((px1 >> 4) == w) && ((py1 >> 1) == l);
    const bool own2 = ((px2 >> 4) == w) && ((py2 >> 1) == l);
    const bool own3 = ((px3 >> 4) == w) && ((py3 >> 1) == l);
    const bool whas0 = __ballot(own0) != 0ULL;   // uniform: this wave holds probe 0
    const bool whas1 = __ballot(own1) != 0ULL;
    const bool whas2 = __ballot(own2) != 0ULL;
    const bool whas3 = __ballot(own3) != 0ULL;
    const int pro0s = __builtin_amdgcn_readfirstlane(px0 & 15);
    const int pro1s = __builtin_amdgcn_readfirstlane(px1 & 15);
    const int pro2s = __builtin_amdgcn_readfirstlane(px2 & 15);
    const int pro3s = __builtin_amdgcn_readfirstlane(px3 & 15);
    const int pel0 = py0 & 1, pel1 = py1 & 1, pel2 = py2 & 1, pel3 = py3 & 1;
    v2f accv0 = zz, accv1 = zz, accv2 = zz, accv3 = zz;

    // source (64,64): wave 4 local i=4 (owner), wave 3 ghost i=20; lane 32 .x
    const bool isw4 = (w == (SRC_XD >> 4));
    const bool isw3 = (w == (SRC_XD >> 4) - 1);
    const bool srcl = (l == (SRC_YD >> 1));

    __syncthreads();

#pragma unroll 1
    for (int t = 0; t < T_STEPSD; t += 4) {
        STEP(a, b, t)          // b <- field(t+1)
        STEP(b, a, t + 1)      // a <- field(t+2)
        STEP(a, b, t + 2)      // b <- field(t+3)
        STEP(b, a, t + 3)      // a <- field(t+4)
        if (t < T_STEPSD - 4) { EXCHANGE }
    }

    if (own0) partial[b * N_PROBESD + 0] = pel0 ? accv0.y : accv0.x;
    if (own1) partial[b * N_PROBESD + 1] = pel1 ? accv1.y : accv1.x;
    if (own2) partial[b * N_PROBESD + 2] = pel2 ? accv2.y : accv2.x;
    if (own3) partial[b * N_PROBESD + 3] = pel3 ? accv3.y : accv3.x;
}

__global__ void reduce_k(const float* __restrict__ partial, float* __restrict__ out) {
    const int p = threadIdx.x;
    if (p < N_PROBESD) {
        float s = 0.0f, tot = 0.0f;
        for (int bb = 0; bb < BATCHD; ++bb) s += partial[bb * N_PROBESD + p];
        for (int i = 0; i < BATCHD * N_PROBESD; ++i) tot += partial[i];
        out[p] = s / tot;
    }
}

extern "C" void kernel_launch(void* const* d_in, const int* in_sizes, int n_in,
                              void* d_out, int out_size, void* d_ws, size_t ws_size,
                              hipStream_t stream) {
    const float* x      = (const float*)d_in[0];
    const float* c      = (const float*)d_in[1];
    const int*   probes = (const int*)d_in[2];
    float* out = (float*)d_out;
    float* partial = (float*)d_ws;

    wave_sim<<<BATCHD, 512, 0, stream>>>(x, c, probes, partial);
    reduce_k<<<1, 64, 0, stream>>>(partial, out);
}

// Round 2
// 235.485 us; speedup vs baseline: 1.1076x; 1.1076x over previous
//
#include <hip/hip_runtime.h>

#define NXD 128
#define NYD 128
#define SRC_XD 64
#define SRC_YD 64
#define T_STEPSD 256
#define BATCHD 8
#define N_PROBESD 4

typedef float v2f __attribute__((ext_vector_type(2)));

// DPP cross-lane single shifts across the full wave64.
// WAVE_SHR1 (0x138): lane i <- lane i-1, lane0 -> 0 (bound_ctrl)
// WAVE_SHL1 (0x130): lane i <- lane i+1, lane63 -> 0
// Zero-fill matches the conv 'SAME' zero padding at col -1 / col 128.
__device__ __forceinline__ float dpp_from_lower(float v) {
    return __int_as_float(__builtin_amdgcn_update_dpp(0, __float_as_int(v), 0x138, 0xF, 0xF, true));
}
__device__ __forceinline__ float dpp_from_upper(float v) {
    return __int_as_float(__builtin_amdgcn_update_dpp(0, __float_as_int(v), 0x130, 0xF, 0xF, true));
}

// Forced packed-f32 math: one instruction per v2f op instead of two.
// gfx950 has v_pk_add_f32 / v_pk_fma_f32 (the 157 TF fp32 path); hipcc does
// not reliably auto-pack ext_vector float math, so we pin it with asm.
// pk_fma(a,b,c) = a*b + c per half, IEEE-identical to contracted scalar fma.
__device__ __forceinline__ v2f pk_add(v2f a, v2f b) {
    v2f d;
    asm("v_pk_add_f32 %0, %1, %2" : "=v"(d) : "v"(a), "v"(b));
    return d;
}
__device__ __forceinline__ v2f pk_fma(v2f a, v2f b, v2f c) {
    v2f d;
    asm("v_pk_fma_f32 %0, %1, %2, %3" : "=v"(d) : "v"(a), "v"(b), "v"(c));
    return d;
}

// One row update (2 cells):
//   lap = up + dn + {lf + Y.y, Y.x + rt} - 4*Y ;  Z = K*lap + (C2 + K2*Z)
// 2 DPP + 2 scalar adds + 5 packed ops.
#define ROW(up, dn, Yr, Zr, Kr) { \
    const float lf = dpp_from_lower((Yr).y); \
    const float rt = dpp_from_upper((Yr).x); \
    v2f cross; cross.x = lf + (Yr).y; cross.y = (Yr).x + rt; \
    const v2f t1  = pk_add((up), (dn)); \
    const v2f t2  = pk_add(t1, cross); \
    const v2f lap = pk_fma((Yr), m4v, t2); \
    const v2f zt  = pk_fma((Zr), K2v, C2v); \
    (Zr) = pk_fma((Kr), lap, zt); \
}

// Wave-uniform 16-way register select (ro is an SGPR via readfirstlane ->
// scalar branch tree, not a cndmask chain).
#define PSEL(ro, Z, pv) switch (ro) { \
    case 0:  pv = (Z##0);  break; \
    case 1:  pv = (Z##1);  break; \
    case 2:  pv = (Z##2);  break; \
    case 3:  pv = (Z##3);  break; \
    case 4:  pv = (Z##4);  break; \
    case 5:  pv = (Z##5);  break; \
    case 6:  pv = (Z##6);  break; \
    case 7:  pv = (Z##7);  break; \
    case 8:  pv = (Z##8);  break; \
    case 9:  pv = (Z##9);  break; \
    case 10: pv = (Z##10); break; \
    case 11: pv = (Z##11); break; \
    case 12: pv = (Z##12); break; \
    case 13: pv = (Z##13); break; \
    default: pv = (Z##14); break; \
    case 15: pv = (Z##15); break; \
}

// One time step: Y = current (read-only), Z = previous, overwritten with new.
// Row order: 1..8 first (independent of the halo ds_reads issued at top, so
// ra/rb latency hides under ~8 rows of VALU), then rows 0 and 15, source add,
// halo publish (early, so the end-of-step barrier finds writes done), then
// rows 9..14 and probe accumulation.
// NOTE: source add hardcodes (Z##0).x -- valid because SRC_XD & 15 == 0 and
// SRC_YD is even, and it happens BEFORE the halo publish of Z##0.
#define STEP(Y, Z, tt, xsv) { \
    const int buf_ = (tt) & 1, nb_ = buf_ ^ 1; \
    const v2f ra = *(const v2f*)&haloBot[buf_][wa][2 * l]; \
    const v2f rb = *(const v2f*)&haloTop[buf_][wb][2 * l]; \
    ROW(Y##0,  Y##2,  Y##1,  Z##1,  k1) \
    ROW(Y##1,  Y##3,  Y##2,  Z##2,  k2) \
    ROW(Y##2,  Y##4,  Y##3,  Z##3,  k3) \
    ROW(Y##3,  Y##5,  Y##4,  Z##4,  k4) \
    ROW(Y##4,  Y##6,  Y##5,  Z##5,  k5) \
    ROW(Y##5,  Y##7,  Y##6,  Z##6,  k6) \
    ROW(Y##6,  Y##8,  Y##7,  Z##7,  k7) \
    ROW(Y##7,  Y##9,  Y##8,  Z##8,  k8) \
    ROW(ra,    Y##1,  Y##0,  Z##0,  k0) \
    ROW(Y##14, rb,    Y##15, Z##15, k15) \
    if (has_src) { if (own_src) (Z##0).x += (xsv); } \
    *(v2f*)&haloTop[nb_][w][2 * l] = (Z##0); \
    *(v2f*)&haloBot[nb_][w][2 * l] = (Z##15); \
    ROW(Y##8,  Y##10, Y##9,  Z##9,  k9) \
    ROW(Y##9,  Y##11, Y##10, Z##10, k10) \
    ROW(Y##10, Y##12, Y##11, Z##11, k11) \
    ROW(Y##11, Y##13, Y##12, Z##12, k12) \
    ROW(Y##12, Y##14, Y##13, Z##13, k13) \
    ROW(Y##13, Y##15, Y##14, Z##14, k14) \
    if (whas0) { v2f pv; PSEL(pro0s, Z, pv) accv0 += pv * pv; } \
    if (whas1) { v2f pv; PSEL(pro1s, Z, pv) accv1 += pv * pv; } \
    if (whas2) { v2f pv; PSEL(pro2s, Z, pv) accv2 += pv * pv; } \
    if (whas3) { v2f pv; PSEL(pro3s, Z, pv) accv3 += pv * pv; } \
    __syncthreads(); \
}

// 512 threads = 8 waves = 2 waves/EU = 1 block/CU. Unified register budget
// at 2 waves/EU is 256/wave -> the full field state (~130 regs) fits in arch
// VGPRs (at 1024 threads the 128-reg cap forced AGPR parking + accvgpr moves).
__global__ __launch_bounds__(512, 2) void wave_sim(
        const float* __restrict__ x,        // (T,B)
        const float* __restrict__ c,        // (NX,NY)
        const int*   __restrict__ probes,   // (4,2) int
        float* __restrict__ partial)        // (B,4)
{
    __shared__ float haloTop[2][9][NYD];    // [8] = permanent zero ghost row
    __shared__ float haloBot[2][9][NYD];
    __shared__ float xs[T_STEPSD];

    const int tid = threadIdx.x;
    const int w = tid >> 6;       // wave 0..7, owns rows 16w..16w+15
    const int l = tid & 63;       // lane, owns cols 2l, 2l+1
    const int b = blockIdx.x;

    const float dt = 0.5f, bdamp = 0.005f;
    const float denom = 1.0f / (dt * dt) + 0.5f * bdamp / dt;  // 4.005
    const float inv_denom = 1.0f / denom;
    const float C2 = 2.0f * inv_denom;
    const float K2 = (-1.0f - dt * bdamp) * inv_denom;
    const float KL = dt * dt * inv_denom;
    v2f C2v; C2v.x = C2; C2v.y = C2;
    v2f K2v; K2v.x = K2; K2v.y = K2;
    v2f m4v; m4v.x = -4.0f; m4v.y = -4.0f;

    for (int i = tid; i < 2 * 9 * NYD; i += 512) {
        ((float*)haloTop)[i] = 0.0f;
        ((float*)haloBot)[i] = 0.0f;
    }
    if (tid < T_STEPSD) xs[tid] = x[tid * BATCHD + b];

    const int rowbase = w * 16;
    const int colb = 2 * l;
#define LOADK(r) \
    v2f k##r; { \
        const v2f cc = *(const v2f*)&c[(rowbase + r) * NYD + colb]; \
        k##r = KL * cc * cc; \
    }
    LOADK(0) LOADK(1) LOADK(2) LOADK(3) LOADK(4) LOADK(5) LOADK(6) LOADK(7)
    LOADK(8) LOADK(9) LOADK(10) LOADK(11) LOADK(12) LOADK(13) LOADK(14) LOADK(15)
#undef LOADK

    v2f zz; zz.x = 0.0f; zz.y = 0.0f;
    v2f a0 = zz, a1 = zz, a2 = zz, a3 = zz, a4 = zz, a5 = zz, a6 = zz, a7 = zz,
        a8 = zz, a9 = zz, a10 = zz, a11 = zz, a12 = zz, a13 = zz, a14 = zz, a15 = zz;
    v2f b0 = zz, b1 = zz, b2 = zz, b3 = zz, b4 = zz, b5 = zz, b6 = zz, b7 = zz,
        b8 = zz, b9 = zz, b10 = zz, b11 = zz, b12 = zz, b13 = zz, b14 = zz, b15 = zz;

    // probes: coordinates are wave-uniform (same global load in every lane)
    const int px0 = probes[0] & 127, py0 = probes[1] & 127;
    const int px1 = probes[2] & 127, py1 = probes[3] & 127;
    const int px2 = probes[4] & 127, py2 = probes[5] & 127;
    const int px3 = probes[6] & 127, py3 = probes[7] & 127;
    const bool own0 = ((px0 >> 4) == w) && ((py0 >> 1) == l);
    const bool own1 = ((px1 >> 4) == w) && ((py1 >> 1) == l);
    const bool own2 = ((px2 >> 4) == w) && ((py2 >> 1) == l);
    const bool own3 = ((px3 >> 4) == w) && ((py3 >> 1) == l);
    const bool whas0 = __ballot(own0) != 0ULL;   // uniform: does THIS wave hold probe 0
    const bool whas1 = __ballot(own1) != 0ULL;
    const bool whas2 = __ballot(own2) != 0ULL;
    const bool whas3 = __ballot(own3) != 0ULL;
    const int pro0s = __builtin_amdgcn_readfirstlane(px0 & 15);
    const int pro1s = __builtin_amdgcn_readfirstlane(px1 & 15);
    const int pro2s = __builtin_amdgcn_readfirstlane(px2 & 15);
    const int pro3s = __builtin_amdgcn_readfirstlane(px3 & 15);
    const int pel0 = py0 & 1, pel1 = py1 & 1, pel2 = py2 & 1, pel3 = py3 & 1;
    v2f accv0 = zz, accv1 = zz, accv2 = zz, accv3 = zz;

    const bool has_src = (w == (SRC_XD >> 4));            // uniform
    const bool own_src = has_src && (l == (SRC_YD >> 1)); // SRC_YD even -> .x

    const int wa = (w == 0) ? 8 : w - 1;    // 8 = zero ghost row
    const int wb = (w == 7) ? 8 : w + 1;

    __syncthreads();

#pragma unroll 1
    for (int t = 0; t < T_STEPSD; t += 2) {
        // one ds_read_b64 covers both steps' source values; consumed mid-step
        const v2f xp = *(const v2f*)&xs[t];
        STEP(a, b, t, xp.x)
        STEP(b, a, t + 1, xp.y)
    }

    if (own0) partial[b * N_PROBESD + 0] = pel0 ? accv0.y : accv0.x;
    if (own1) partial[b * N_PROBESD + 1] = pel1 ? accv1.y : accv1.x;
    if (own2) partial[b * N_PROBESD + 2] = pel2 ? accv2.y : accv2.x;
    if (own3) partial[b * N_PROBESD + 3] = pel3 ? accv3.y : accv3.x;
}

__global__ void reduce_k(const float* __restrict__ partial, float* __restrict__ out) {
    const int p = threadIdx.x;
    if (p < N_PROBESD) {
        float s = 0.0f, tot = 0.0f;
        for (int bb = 0; bb < BATCHD; ++bb) s += partial[bb * N_PROBESD + p];
        for (int i = 0; i < BATCHD * N_PROBESD; ++i) tot += partial[i];
        out[p] = s / tot;
    }
}

extern "C" void kernel_launch(void* const* d_in, const int* in_sizes, int n_in,
                              void* d_out, int out_size, void* d_ws, size_t ws_size,
                              hipStream_t stream) {
    const float* x      = (const float*)d_in[0];
    const float* c      = (const float*)d_in[1];
    const int*   probes = (const int*)d_in[2];
    float* out = (float*)d_out;
    float* partial = (float*)d_ws;

    wave_sim<<<BATCHD, 512, 0, stream>>>(x, c, probes, partial);
    reduce_k<<<1, 64, 0, stream>>>(partial, out);
}